// Round 10
// baseline (377.610 us; speedup 1.0000x reference)
//
#include <hip/hip_runtime.h>

#define NB 4
#define NH 16
#define NSQ 1024
#define NSKV 1024
#define ND 64

typedef __attribute__((ext_vector_type(8))) short short8;
typedef __attribute__((ext_vector_type(4))) float f32x4;
typedef __attribute__((ext_vector_type(4))) int int4v;
typedef __attribute__((ext_vector_type(4))) unsigned int uint4v;
typedef __attribute__((ext_vector_type(2))) unsigned int uint2v;

__device__ __forceinline__ unsigned int cvt_pk(float lo, float hi) {
  unsigned int r;
  asm("v_cvt_pk_bf16_f32 %0, %1, %2" : "=v"(r) : "v"(lo), "v"(hi));
  return r;
}
__device__ __forceinline__ unsigned short f2bf(float f) {
  unsigned int u = __float_as_uint(f);
  u += 0x7FFFu + ((u >> 16) & 1u);
  return (unsigned short)(u >> 16);
}
__device__ __forceinline__ void bar() { __builtin_amdgcn_s_barrier(); }
__device__ __forceinline__ void lgkm0() {
  asm volatile("s_waitcnt lgkmcnt(0)" ::: "memory");
}

// TWO-SWEEP RECOMPUTE design: no P stash, no store epilogue.
// 256 threads = 4 waves; wave w owns q-rows [q0+w*16,+16) and sweeps the FULL
// kv range (no merge needed). Sweep 1: stage K (gang, 4KB) -> QK^T -> exp ->
// row sums. Sweep 2: stage K+V, recompute P, write W=pe*rcp STREAMING to
// global, 1KB/wave Ps round-trip feeds PV MFMA -> ctx.
// LDS = 13.3KB -> with __launch_bounds__(256,4): 4 blocks/CU (16 waves/CU);
// sibling blocks cover each other's barrier/memory stalls.
// SWAPPED QK^T: mfma(A=K,B=Q) -> lane (lg,lm) holds P[q=lm][kv=sub*16+lg*4+j]
// so A/M are float4/int4 there, W stores are float4, rcp is lane-local.
__global__ __launch_bounds__(256, 4)
void attn_fused(const float* __restrict__ Q, const float* __restrict__ K,
                const float* __restrict__ V, const int* __restrict__ M,
                const float* __restrict__ A, float* __restrict__ Octx,
                float* __restrict__ Ow)
{
  __shared__ __align__(16) unsigned char Ks[4096];   // [32 kv][128B] XOR (row&7)<<4
  __shared__ __align__(16) unsigned char Vt[5120];   // [64 d][80B]  XOR ((d>>2)&3)<<4
  __shared__ __align__(16) unsigned char Ps[4096];   // per-wave 1KB: [16 q][64B] XOR (lm&3)<<4

  const int t  = threadIdx.x;
  const int w  = t >> 6;
  const int l  = t & 63;
  const int lg = l >> 4;
  const int lm = l & 15;

  // XCD swizzle: 16 consecutive q-tiles of one bh share an XCD (K/V L2-hot)
  const int bid = blockIdx.x;           // 1024 blocks
  const int y   = bid >> 3;
  const int qt  = y & 15;
  const int bh  = (bid & 7) + (y >> 4) * 8;
  const int b   = bh >> 4;
  const int q0  = qt * 64;
  const int qw  = q0 + w * 16;          // this wave's 16 q-rows

  const float* Qp = Q + (size_t)bh * NSQ * ND;
  const float* Kp = K + (size_t)bh * NSKV * ND;
  const float* Vp = V + (size_t)bh * NSKV * ND;
  const float* Ap = A + (size_t)bh * NSQ * NSKV;
  const int*   Mp = M + (size_t)b  * NSQ * NSKV;

  unsigned char* Psw = Ps + w * 1024;

  const float C = 0.18033688011112042f;  // 0.125 * log2(e)

  // Q fragment (B operand): lane holds Q[qw+lm][dc*32+lg*8+e]
  short8 qf[2];
  {
    const float* qr = Qp + (size_t)(qw + lm) * ND + lg * 8;
    #pragma unroll
    for (int dc = 0; dc < 2; ++dc) {
      f32x4 x = *(const f32x4*)(qr + dc * 32);
      f32x4 y2 = *(const f32x4*)(qr + dc * 32 + 4);
      uint4v u;
      u[0] = cvt_pk(x[0], x[1]); u[1] = cvt_pk(x[2], x[3]);
      u[2] = cvt_pk(y2[0], y2[1]); u[3] = cvt_pk(y2[2], y2[3]);
      qf[dc] = __builtin_bit_cast(short8, u);
    }
  }

  f32x4 ctx[4];
  #pragma unroll
  for (int i = 0; i < 4; ++i) ctx[i] = (f32x4){0.f, 0.f, 0.f, 0.f};
  float sum = 0.f;

  f32x4 aA[2], aB[2];  int4v mA[2], mB[2];   // A/M one chunk ahead
  f32x4 skA[2], skB[2], svA[2], svB[2];      // gang staging regs

  auto loadAM = [&](int kv0, f32x4* a, int4v* m) {
    #pragma unroll
    for (int sub = 0; sub < 2; ++sub) {
      size_t off = (size_t)(qw + lm) * NSKV + kv0 + sub * 16 + lg * 4;
      a[sub] = *(const f32x4*)(Ap + off);
      m[sub] = *(const int4v*)(Mp + off);
    }
  };
  // chunk = 32 kv x 64 d = 2048 f32 contiguous; thread t takes f32[t*4 + i*1024]
  auto issueK = [&](int kv0, f32x4* sk) {
    const float* kb = Kp + (size_t)kv0 * ND + t * 4;
    sk[0] = *(const f32x4*)kb;
    sk[1] = *(const f32x4*)(kb + 1024);
  };
  auto issueV = [&](int kv0, f32x4* sv) {
    const float* vb = Vp + (size_t)kv0 * ND + t * 4;
    sv[0] = *(const f32x4*)vb;
    sv[1] = *(const f32x4*)(vb + 1024);
  };
  auto writeK = [&](const f32x4* sk) {
    #pragma unroll
    for (int i = 0; i < 2; ++i) {
      int f = t * 4 + i * 1024, row = f >> 6, c0 = f & 63;
      uint2v ku;
      ku[0] = cvt_pk(sk[i][0], sk[i][1]); ku[1] = cvt_pk(sk[i][2], sk[i][3]);
      *(uint2v*)(Ks + row * 128 + ((c0 * 2) ^ ((row & 7) << 4))) = ku;
    }
  };
  auto writeV = [&](const f32x4* sv) {
    #pragma unroll
    for (int i = 0; i < 2; ++i) {
      int f = t * 4 + i * 1024, row = f >> 6, c0 = f & 63;
      #pragma unroll
      for (int j = 0; j < 4; ++j) {
        int d = c0 + j;
        *(unsigned short*)(Vt + d * 80 + ((row * 2) ^ (((d >> 2) & 3) << 4))) =
            f2bf(sv[i][j]);
      }
    }
  };
  auto loadKf = [&](short8* kf) {
    const int ksw = (lm & 7) << 4;
    #pragma unroll
    for (int sub = 0; sub < 2; ++sub)
      #pragma unroll
      for (int dc = 0; dc < 2; ++dc)
        kf[sub * 2 + dc] = *(const short8*)(
            Ks + (sub * 16 + lm) * 128 + ((dc * 64 + lg * 16) ^ ksw));
  };

  // ---------------- SWEEP 1: row sums only ----------------
  auto computeS1 = [&](const f32x4* a, const int4v* m) {
    short8 kf[4];
    loadKf(kf);
    #pragma unroll
    for (int sub = 0; sub < 2; ++sub) {
      f32x4 acc = (f32x4){0.f, 0.f, 0.f, 0.f};
      #pragma unroll
      for (int dc = 0; dc < 2; ++dc)
        acc = __builtin_amdgcn_mfma_f32_16x16x32_bf16(kf[sub * 2 + dc], qf[dc],
                                                      acc, 0, 0, 0);
      #pragma unroll
      for (int j = 0; j < 4; ++j) {
        float amc = m[sub][j] ? a[sub][j] * C : -1.8e8f;
        sum += exp2f(fmaf(acc[j], C, amc));   // masked -> exact 0
      }
    }
  };

  issueK(0, skA);
  loadAM(0, aA, mA);
  for (int c = 0; c < 32; c += 2) {
    bar();                                  // Ks readers of prev chunk done
    writeK(skA);                            // counted-vmcnt wait on skA
    issueK((c + 1) * 32, skB); loadAM((c + 1) * 32, aB, mB);
    lgkm0(); bar();                         // Ks visible
    computeS1(aA, mA);
    bar();
    writeK(skB);
    if (c < 30) { issueK((c + 2) * 32, skA); loadAM((c + 2) * 32, aA, mA); }
    lgkm0(); bar();
    computeS1(aB, mB);
  }

  // complete row sums across the 4 lg-lanes sharing q=lm; rcp is lane-local
  sum += __shfl_xor(sum, 16);
  sum += __shfl_xor(sum, 32);
  const float rcp = 1.0f / sum;

  // ---------------- SWEEP 2: W streaming + PV ----------------
  float* OwRow = Ow + (size_t)bh * NSQ * NSKV + (size_t)(qw + lm) * NSKV;

  auto computeS2 = [&](int kv0, const f32x4* a, const int4v* m) {
    short8 kf[4];
    loadKf(kf);
    const int vsw = ((lm >> 2) & 3) << 4;
    short8 vf[4];
    #pragma unroll
    for (int ds = 0; ds < 4; ++ds)
      vf[ds] = *(const short8*)(Vt + (ds * 16 + lm) * 80 + ((lg * 16) ^ vsw));

    #pragma unroll
    for (int sub = 0; sub < 2; ++sub) {
      f32x4 acc = (f32x4){0.f, 0.f, 0.f, 0.f};
      #pragma unroll
      for (int dc = 0; dc < 2; ++dc)
        acc = __builtin_amdgcn_mfma_f32_16x16x32_bf16(kf[sub * 2 + dc], qf[dc],
                                                      acc, 0, 0, 0);
      float pe[4];
      #pragma unroll
      for (int j = 0; j < 4; ++j) {
        float amc = m[sub][j] ? a[sub][j] * C : -1.8e8f;
        pe[j] = exp2f(fmaf(acc[j], C, amc));
      }
      // W stream out (64B segments, fire-and-forget)
      f32x4 o;
      o[0] = pe[0] * rcp; o[1] = pe[1] * rcp;
      o[2] = pe[2] * rcp; o[3] = pe[3] * rcp;
      *(f32x4*)(OwRow + kv0 + sub * 16 + lg * 4) = o;
      // tiny Ps round-trip for the PV transpose
      uint2v u2;
      u2[0] = cvt_pk(pe[0], pe[1]); u2[1] = cvt_pk(pe[2], pe[3]);
      *(uint2v*)(Psw + lm * 64 + (((sub * 32 + lg * 8)) ^ ((lm & 3) << 4))) = u2;
    }
    // own-wave Ps RAW fence (rule #18)
    lgkm0();
    __builtin_amdgcn_sched_barrier(0);
    short8 pf = *(const short8*)(Psw + lm * 64 + ((lg * 16) ^ ((lm & 3) << 4)));
    #pragma unroll
    for (int ds = 0; ds < 4; ++ds)
      ctx[ds] = __builtin_amdgcn_mfma_f32_16x16x32_bf16(pf, vf[ds], ctx[ds], 0, 0, 0);
  };

  issueK(0, skA); issueV(0, svA);
  loadAM(0, aA, mA);
  for (int c = 0; c < 32; c += 2) {
    bar();                                  // Ks/Vt readers of prev chunk done
    writeK(skA); writeV(svA);
    issueK((c + 1) * 32, skB); issueV((c + 1) * 32, svB);
    loadAM((c + 1) * 32, aB, mB);
    lgkm0(); bar();
    computeS2(c * 32, aA, mA);
    bar();
    writeK(skB); writeV(svB);
    if (c < 30) {
      issueK((c + 2) * 32, skA); issueV((c + 2) * 32, svA);
      loadAM((c + 2) * 32, aA, mA);
    }
    lgkm0(); bar();
    computeS2((c + 1) * 32, aB, mB);
  }

  // ---- context out: rcp for q=lg*4+j via in-wave shuffle ----
  #pragma unroll
  for (int ds = 0; ds < 4; ++ds)
    #pragma unroll
    for (int j = 0; j < 4; ++j) {
      float rc = __shfl(rcp, lg * 4 + j);
      Octx[((size_t)bh * NSQ + qw + lg * 4 + j) * ND + ds * 16 + lm] =
          ctx[ds][j] * rc;
    }
}

extern "C" void kernel_launch(void* const* d_in, const int* in_sizes, int n_in,
                              void* d_out, int out_size, void* d_ws, size_t ws_size,
                              hipStream_t stream) {
  const float* Q = (const float*)d_in[0];
  const float* K = (const float*)d_in[1];
  const float* V = (const float*)d_in[2];
  const int*   M = (const int*)d_in[3];
  const float* A = (const float*)d_in[4];
  float* ctx = (float*)d_out;
  float* wts = ctx + (size_t)NB * NH * NSQ * ND;  // outputs: (context, weights)
  dim3 grid(NB * NH * (NSQ / 64));                // 1024 blocks
  attn_fused<<<grid, dim3(256), 0, stream>>>(Q, K, V, M, A, ctx, wts);
}

// Round 11
// 190.992 us; speedup vs baseline: 1.9771x; 1.9771x over previous
//
#include <hip/hip_runtime.h>

#define NB 4
#define NH 16
#define NSQ 1024
#define NSKV 1024
#define ND 64

typedef __attribute__((ext_vector_type(8))) short short8;
typedef __attribute__((ext_vector_type(4))) float f32x4;
typedef __attribute__((ext_vector_type(4))) int int4v;
typedef __attribute__((ext_vector_type(4))) unsigned int uint4v;
typedef __attribute__((ext_vector_type(2))) unsigned int uint2v;

__device__ __forceinline__ unsigned int cvt_pk(float lo, float hi) {
  unsigned int r;
  asm("v_cvt_pk_bf16_f32 %0, %1, %2" : "=v"(r) : "v"(lo), "v"(hi));
  return r;
}
__device__ __forceinline__ unsigned short f2bf(float f) {
  unsigned int u = __float_as_uint(f);
  u += 0x7FFFu + ((u >> 16) & 1u);
  return (unsigned short)(u >> 16);
}
__device__ __forceinline__ float bf2f(unsigned short h) {
  return __uint_as_float(((unsigned int)h) << 16);
}
__device__ __forceinline__ void bar() { __builtin_amdgcn_s_barrier(); }
__device__ __forceinline__ void lgkm0() {
  asm volatile("s_waitcnt lgkmcnt(0)" ::: "memory");
}

// R6 champion structure + PHASE-STAGGERED halves:
// 512 threads = 8 waves: p=w&3 -> q-rows [q0+p*16,+16); h=w>>2 -> kv half.
// While half-0 stages its next chunk (vmem issue + ds_writes), half-1
// computes its current chunk (ds_reads + MFMA + exp) -- and vice versa,
// alternating each barrier. Same barrier count as R6, but every interval
// now has a balanced resource mix and one gang's waits hide under the
// other gang's compute. XCD-clustered bid decode; setprio around MFMA.
// All data-layout formulas identical to R6 (verified passing).
__global__ __launch_bounds__(512, 2)
void attn_fused(const float* __restrict__ Q, const float* __restrict__ K,
                const float* __restrict__ V, const int* __restrict__ M,
                const float* __restrict__ A, float* __restrict__ Octx,
                float* __restrict__ Ow)
{
  __shared__ unsigned short Ps[64 * 1024];       // 128 KB, rows 2048B, XOR (lm<<4)
  __shared__ __align__(16) unsigned char Stg[18432]; // staging; CtxS overlay post-sweep
  __shared__ float SumS[64][2];

  const int t  = threadIdx.x;
  const int w  = t >> 6;
  const int l  = t & 63;
  const int lg = l >> 4;       // 0..3
  const int lm = l & 15;
  const int p  = w & 3;        // q-row pair id
  const int h  = w >> 2;       // kv half
  const int g  = p * 64 + l;   // gang lane within half (0..255)

  // XCD clustering: each bh's 16 q-tiles land on ONE XCD (K/V L2-resident)
  const int bid = blockIdx.x;            // 1024 blocks
  const int y   = bid >> 3;
  const int qt  = y & 15;                // 16 q-tiles of 64 rows
  const int bh  = (bid & 7) * 8 + (y >> 4);
  const int b   = bh >> 4;
  const int q0  = qt * 64;
  const int kvb = h * 512;

  unsigned char* KsB = Stg + h * 4096;           // [32 rows][128B], XOR (row&7)<<4
  unsigned char* VtB = Stg + 8192 + h * 5120;    // [64 d-rows][80B], XOR ((d>>2)&3)<<4

  const float* Qp = Q + (size_t)bh * NSQ * ND;
  const float* Kp = K + (size_t)bh * NSKV * ND;
  const float* Vp = V + (size_t)bh * NSKV * ND;
  const float* Ap = A + (size_t)bh * NSQ * NSKV;
  const int*   Mp = M + (size_t)b  * NSQ * NSKV;

  const float C = 0.18033688011112042f;  // 0.125 * log2(e)

  // Q fragment (B operand of QK^T): lane holds Q[qw+lm][dc*32+lg*8+e]
  short8 qf[2];
  {
    const float* qr = Qp + (size_t)(q0 + p * 16 + lm) * ND + lg * 8;
    #pragma unroll
    for (int dc = 0; dc < 2; ++dc) {
      f32x4 x = *(const f32x4*)(qr + dc * 32);
      f32x4 y2 = *(const f32x4*)(qr + dc * 32 + 4);
      uint4v u;
      u[0] = cvt_pk(x[0], x[1]); u[1] = cvt_pk(x[2], x[3]);
      u[2] = cvt_pk(y2[0], y2[1]); u[3] = cvt_pk(y2[2], y2[3]);
      qf[dc] = __builtin_bit_cast(short8, u);
    }
  }

  f32x4 ctx[4];
  #pragma unroll
  for (int i = 0; i < 4; ++i) ctx[i] = (f32x4){0.f, 0.f, 0.f, 0.f};
  float sum = 0.f;

  f32x4 sk[2], sv[2];                        // staging regs (one chunk in flight)
  f32x4 aA[2], aB[2];  int4v mA[2], mB[2];   // A/M alternating buffers

  // chunk = 32 kv x 64 d = 2048 f32 contiguous; gang lane g takes g*4 + i*1024
  auto issueStage = [&](int c) {
    int kv0 = kvb + c * 32;
    const float* kb = Kp + (size_t)kv0 * ND + g * 4;
    const float* vb = Vp + (size_t)kv0 * ND + g * 4;
    sk[0] = *(const f32x4*)kb;       sk[1] = *(const f32x4*)(kb + 1024);
    sv[0] = *(const f32x4*)vb;       sv[1] = *(const f32x4*)(vb + 1024);
  };
  auto loadAM = [&](int c, f32x4* a, int4v* m) {
    int kv0 = kvb + c * 32;
    #pragma unroll
    for (int sub = 0; sub < 2; ++sub) {
      size_t off = (size_t)(q0 + p * 16 + lm) * NSKV + kv0 + sub * 16 + lg * 4;
      a[sub] = *(const f32x4*)(Ap + off);
      m[sub] = *(const int4v*)(Mp + off);
    }
  };
  auto writeStage = [&]() {                  // R6-proven formulas
    #pragma unroll
    for (int i = 0; i < 2; ++i) {
      int f = g * 4 + i * 1024;
      int row = f >> 6;                 // kv-local
      int cb  = (f & 63) * 2;           // byte col in 128B row (8B-aligned)
      uint2v u;
      u[0] = cvt_pk(sk[i][0], sk[i][1]);
      u[1] = cvt_pk(sk[i][2], sk[i][3]);
      *(uint2v*)(KsB + row * 128 + (cb ^ ((row & 7) << 4))) = u;
      int kv = row, d0 = f & 63;
      #pragma unroll
      for (int j = 0; j < 4; ++j) {
        int d = d0 + j;
        *(unsigned short*)(VtB + d * 80 + ((kv * 2) ^ (((d >> 2) & 3) << 4))) =
            f2bf(sv[i][j]);
      }
    }
  };

  auto compute = [&](int c, const f32x4* a, const int4v* m) {
    int kv0 = kvb + c * 32;
    const int ksw = (lm & 7) << 4;
    const int vsw = ((lm >> 2) & 3) << 4;
    short8 kf[4];
    #pragma unroll
    for (int sub = 0; sub < 2; ++sub)
      #pragma unroll
      for (int dc = 0; dc < 2; ++dc)
        kf[sub * 2 + dc] = *(const short8*)(
            KsB + (sub * 16 + lm) * 128 + ((dc * 64 + lg * 16) ^ ksw));
    short8 vf[4];
    #pragma unroll
    for (int ds = 0; ds < 4; ++ds)
      vf[ds] = *(const short8*)(VtB + (ds * 16 + lm) * 80 + ((lg * 16) ^ vsw));

    __builtin_amdgcn_s_setprio(1);
    // QK^T (A=K,B=Q): acc[j] = logit(q=lm, kv=kv0+sub*16+lg*4+j)
    #pragma unroll
    for (int sub = 0; sub < 2; ++sub) {
      f32x4 acc = (f32x4){0.f, 0.f, 0.f, 0.f};
      #pragma unroll
      for (int dc = 0; dc < 2; ++dc)
        acc = __builtin_amdgcn_mfma_f32_16x16x32_bf16(kf[sub * 2 + dc], qf[dc],
                                                      acc, 0, 0, 0);
      float pe[4];
      #pragma unroll
      for (int j = 0; j < 4; ++j) {
        float amc = m[sub][j] ? a[sub][j] * C : -1.8e8f;
        pe[j] = exp2f(fmaf(acc[j], C, amc));   // masked -> exact 0
        sum += pe[j];
      }
      uint2v u2;
      u2[0] = cvt_pk(pe[0], pe[1]); u2[1] = cvt_pk(pe[2], pe[3]);
      *(uint2v*)((char*)Ps + (p * 16 + lm) * 2048 +
                 (((kv0 + sub * 16 + lg * 4) * 2) ^ (lm << 4))) = u2;
    }
    // own-wave Ps RAW fence (rule #18)
    lgkm0();
    __builtin_amdgcn_sched_barrier(0);
    // PV: pf = P[q=lm][kv0+lg*8..+7]; same k-map as vf
    short8 pf = *(const short8*)((char*)Ps + (p * 16 + lm) * 2048 +
                                 (((kv0 + lg * 8) * 2) ^ (lm << 4)));
    #pragma unroll
    for (int ds = 0; ds < 4; ++ds)
      ctx[ds] = __builtin_amdgcn_mfma_f32_16x16x32_bf16(pf, vf[ds], ctx[ds], 0, 0, 0);
    __builtin_amdgcn_s_setprio(0);
  };

  // ---- prologue: h0 stages chunk0 to regs; h1 additionally writes it and
  // issues chunk1 (phase offset). AM: amA=chunk0; h1 also amB=chunk1.
  issueStage(0);
  loadAM(0, aA, mA);
  if (h == 1) {
    writeStage();                 // vmcnt wait on chunk0 loads
    issueStage(1);                // chunk1 in flight
    loadAM(1, aB, mB);
  }
  lgkm0(); bar();

  // ---- staggered sweep: 16 chunks per half, unrolled x2 for static bufs ----
  for (int c = 0; c < 16; c += 2) {
    int n1 = (c + 1 > 15) ? 15 : c + 1;
    int n2 = (c + 2 > 15) ? 15 : c + 2;
    int n3 = (c + 3 > 15) ? 15 : c + 3;
    // phase A1: h0 stages chunk c | h1 computes chunk c
    if (h == 0) { writeStage(); issueStage(n1); loadAM(n1, aB, mB); }
    else        { compute(c, aA, mA); }
    lgkm0(); bar();
    // phase B1: h0 computes chunk c | h1 stages chunk c+1
    if (h == 0) { compute(c, aA, mA); }
    else        { writeStage(); issueStage(n2); loadAM(n2, aA, mA); }
    lgkm0(); bar();
    // phase A2: h0 stages chunk c+1 | h1 computes chunk c+1
    if (h == 0) { writeStage(); issueStage(n2); loadAM(n2, aA, mA); }
    else        { compute(c + 1, aB, mB); }
    lgkm0(); bar();
    // phase B2: h0 computes chunk c+1 | h1 stages chunk c+2
    if (h == 0) { compute(c + 1, aB, mB); }
    else        { writeStage(); issueStage(n3); loadAM(n3, aB, mB); }
    lgkm0(); bar();
  }

  // ---- merge halves (R6-verbatim epilogue) ----
  sum += __shfl_xor(sum, 16);
  sum += __shfl_xor(sum, 32);
  if (lg == 0) SumS[p * 16 + lm][h] = sum;
  lgkm0(); bar();                        // all sweeps done; staging dead

  float (*CtxS)[16][64] = (float(*)[16][64])Stg;   // overlay staging area
  if (h == 1) {
    #pragma unroll
    for (int ds = 0; ds < 4; ++ds)
      #pragma unroll
      for (int j = 0; j < 4; ++j)
        CtxS[p][lg * 4 + j][ds * 16 + lm] = ctx[ds][j];
  }
  lgkm0(); bar();

  if (h == 0) {
    float rcpj[4];
    #pragma unroll
    for (int j = 0; j < 4; ++j) {
      int r = p * 16 + lg * 4 + j;
      rcpj[j] = 1.0f / (SumS[r][0] + SumS[r][1]);
    }
    #pragma unroll
    for (int ds = 0; ds < 4; ++ds)
      #pragma unroll
      for (int j = 0; j < 4; ++j)
        Octx[((size_t)bh * NSQ + q0 + p * 16 + lg * 4 + j) * ND + ds * 16 + lm] =
            (ctx[ds][j] + CtxS[p][lg * 4 + j][ds * 16 + lm]) * rcpj[j];
  }

  // ---- weights out: wave writes its own 16 rows x its 512-kv half ----
  float* Owp = Ow + (size_t)bh * NSQ * NSKV + (size_t)(q0 + p * 16) * NSKV;
  for (int r = 0; r < 16; ++r) {
    float rr = 1.0f / (SumS[p * 16 + r][0] + SumS[p * 16 + r][1]);
    int kv = kvb + l * 8;
    short8 pv = *(const short8*)((char*)Ps + (p * 16 + r) * 2048 +
                                 ((kv * 2) ^ (r << 4)));
    f32x4 o1, o2;
    o1[0] = bf2f((unsigned short)pv[0]) * rr;
    o1[1] = bf2f((unsigned short)pv[1]) * rr;
    o1[2] = bf2f((unsigned short)pv[2]) * rr;
    o1[3] = bf2f((unsigned short)pv[3]) * rr;
    o2[0] = bf2f((unsigned short)pv[4]) * rr;
    o2[1] = bf2f((unsigned short)pv[5]) * rr;
    o2[2] = bf2f((unsigned short)pv[6]) * rr;
    o2[3] = bf2f((unsigned short)pv[7]) * rr;
    *(f32x4*)&Owp[(size_t)r * NSKV + kv]     = o1;
    *(f32x4*)&Owp[(size_t)r * NSKV + kv + 4] = o2;
  }
}

extern "C" void kernel_launch(void* const* d_in, const int* in_sizes, int n_in,
                              void* d_out, int out_size, void* d_ws, size_t ws_size,
                              hipStream_t stream) {
  const float* Q = (const float*)d_in[0];
  const float* K = (const float*)d_in[1];
  const float* V = (const float*)d_in[2];
  const int*   M = (const int*)d_in[3];
  const float* A = (const float*)d_in[4];
  float* ctx = (float*)d_out;
  float* wts = ctx + (size_t)NB * NH * NSQ * ND;  // outputs: (context, weights)
  dim3 grid(NB * NH * (NSQ / 64));                // 1024 blocks
  attn_fused<<<grid, dim3(512), 0, stream>>>(Q, K, V, M, A, ctx, wts);
}